// Round 2
// baseline (68.941 us; speedup 1.0000x reference)
//
#include <hip/hip_runtime.h>

#define NB   8
#define NQL  2048
#define NKL  2048
#define DD   64
#define DVV  64

typedef __attribute__((ext_vector_type(8))) short bf16x8;
typedef __attribute__((ext_vector_type(4))) short bf16x4;
typedef __attribute__((ext_vector_type(8))) unsigned short u16x8;
typedef __attribute__((ext_vector_type(4))) float f32x4;

#define L2E 1.44269504088896340736f

__device__ __forceinline__ unsigned short f2bf(float x) {
    union { float f; unsigned u; } v; v.f = x;
    unsigned r = v.u + 0x7FFFu + ((v.u >> 16) & 1u);
    return (unsigned short)(r >> 16);
}

// ---------------- pre-kernels: one-time fp32 -> bf16 staging ----------------

// K [b][key][d] fp32 -> bf16 same layout. 8 elems/thread.
__global__ __launch_bounds__(256)
void cvt_k(const float* __restrict__ K, unsigned short* __restrict__ Kw) {
    int i = blockIdx.x * 256 + threadIdx.x;          // i indexes groups of 8
    const f32x4* src = (const f32x4*)(K + (size_t)i * 8);
    f32x4 a = src[0], b = src[1];
    u16x8 o;
#pragma unroll
    for (int j = 0; j < 4; ++j) { o[j] = f2bf(a[j]); o[4 + j] = f2bf(b[j]); }
    *(u16x8*)(Kw + (size_t)i * 8) = o;
}

// V [b][key][dv] fp32 -> Vt [b][dv][key] bf16 (transposed), via LDS tile.
__global__ __launch_bounds__(256)
void tr_v(const float* __restrict__ V, unsigned short* __restrict__ Vt) {
    const int b  = blockIdx.x & 7;
    const int k0 = (blockIdx.x >> 3) << 6;           // key chunk of 64
    __shared__ float tile[64][65];
    const float* Vb = V + ((size_t)b * NKL + k0) * DVV;
    const int col  = threadIdx.x & 63;
    const int row4 = threadIdx.x >> 6;               // 0..3
#pragma unroll
    for (int i = 0; i < 16; ++i) {
        int r = i * 4 + row4;
        tile[r][col] = Vb[(size_t)r * DVV + col];
    }
    __syncthreads();
    unsigned short* Vtb = Vt + (size_t)b * DVV * NKL;
#pragma unroll
    for (int i = 0; i < 16; ++i) {
        int dv = i * 4 + row4;
        Vtb[(size_t)dv * NKL + k0 + col] = f2bf(tile[col][dv]);
    }
}

// ---------------- main kernel (bf16-staged fast path) ----------------

__global__ __launch_bounds__(256, 4)
void attn_fwd2(const float* __restrict__ Qg,
               const unsigned short* __restrict__ Kw,
               const unsigned short* __restrict__ Vtw,
               float* __restrict__ Og)
{
    const int tid  = threadIdx.x;
    const int wv   = tid >> 6;
    const int lane = tid & 63;
    const int c    = lane & 15;     // q within tile (C/D col)
    const int h    = lane >> 4;

    const int bid = blockIdx.x;
    const int b   = bid & 7;
    const int qt  = bid >> 3;
    const int q0  = qt << 4;

    const float*          Qb  = Qg  + (size_t)b * NQL * DD;
    const unsigned short* Kb  = Kw  + (size_t)b * NKL * DD;
    const unsigned short* Vtb = Vtw + (size_t)b * DVV * NKL;

    // Q fragments (B-operand), scale folded. slot (h,j) of dh = Q[q0+c][dh*32+8h+j]
    bf16x8 qf[2];
#pragma unroll
    for (int dh = 0; dh < 2; ++dh) {
        const float* src = Qb + (size_t)(q0 + c) * DD + dh * 32 + h * 8;
        f32x4 x0 = *(const f32x4*)(src);
        f32x4 x1 = *(const f32x4*)(src + 4);
        bf16x8 t;
#pragma unroll
        for (int j = 0; j < 4; ++j) {
            t[j]     = (short)f2bf(x0[j] * 0.125f);
            t[4 + j] = (short)f2bf(x1[j] * 0.125f);
        }
        qf[dh] = t;
    }

    float m = -INFINITY;
    float l = 0.0f;
    f32x4 acc[4];
    {
        f32x4 z = {0.f, 0.f, 0.f, 0.f};
#pragma unroll
        for (int s = 0; s < 4; ++s) acc[s] = z;
    }

    const int nkt = (q0 + 47) >> 5;

    for (int kt = wv; kt < nkt; kt += 4) {
        const int kb = kt << 5;

        // ---- QK^T
        f32x4 st[2];
        {
            f32x4 z = {0.f, 0.f, 0.f, 0.f};
            st[0] = z; st[1] = z;
        }
#pragma unroll
        for (int t = 0; t < 2; ++t) {
#pragma unroll
            for (int dh = 0; dh < 2; ++dh) {
                bf16x8 kf = *(const bf16x8*)(Kb + (size_t)(kb + t * 16 + c) * DD + dh * 32 + h * 8);
                st[t] = __builtin_amdgcn_mfma_f32_16x16x32_bf16(kf, qf[dh], st[t], 0, 0, 0);
            }
        }

        // ---- causal mask: st[t][r] is (key = kb+16t+4h+r, q = q0+c)
        if (kb + 31 > q0) {
#pragma unroll
            for (int t = 0; t < 2; ++t)
#pragma unroll
                for (int r = 0; r < 4; ++r) {
                    int key = kb + t * 16 + h * 4 + r;
                    if (key > q0 + c) st[t][r] = -1e9f;
                }
        }

        // ---- online softmax with defer-max (THR=8)
        float vmax = st[0][0];
#pragma unroll
        for (int t = 0; t < 2; ++t)
#pragma unroll
            for (int r = 0; r < 4; ++r) vmax = fmaxf(vmax, st[t][r]);
        vmax = fmaxf(vmax, __shfl_xor(vmax, 16));
        vmax = fmaxf(vmax, __shfl_xor(vmax, 32));

        if (!__all(vmax - m <= 8.0f)) {
            float mn    = fmaxf(m, vmax);
            float alpha = exp2f((m - mn) * L2E);
            l *= alpha;
#pragma unroll
            for (int s = 0; s < 4; ++s)
#pragma unroll
                for (int r = 0; r < 4; ++r) acc[s][r] *= alpha;
            m = mn;
        }

        float p[2][4];
        float ps = 0.f;
#pragma unroll
        for (int t = 0; t < 2; ++t)
#pragma unroll
            for (int r = 0; r < 4; ++r) {
                p[t][r] = exp2f((st[t][r] - m) * L2E);
                ps += p[t][r];
            }
        ps += __shfl_xor(ps, 16);
        ps += __shfl_xor(ps, 32);
        l += ps;

        // ---- P^T fragment: slot (h,j) = P[key = kb+4h+(j&3)+16*(j>>2)][q0+c]
        bf16x8 pf;
#pragma unroll
        for (int j = 0; j < 8; ++j) pf[j] = (short)f2bf(p[j >> 2][j & 3]);

        // ---- V^T fragments from transposed bf16 V: two contiguous 4-key runs
#pragma unroll
        for (int s = 0; s < 4; ++s) {
            const unsigned short* vr = Vtb + (size_t)(c + 16 * s) * NKL + kb + 4 * h;
            bf16x4 lo = *(const bf16x4*)(vr);
            bf16x4 hi = *(const bf16x4*)(vr + 16);
            bf16x8 vf = {lo[0], lo[1], lo[2], lo[3], hi[0], hi[1], hi[2], hi[3]};
            acc[s] = __builtin_amdgcn_mfma_f32_16x16x32_bf16(vf, pf, acc[s], 0, 0, 0);
        }
    }

    // ---- flash-combine the 4 key-split waves via LDS
    __shared__ float Osc[4][64][17];
    __shared__ float Msc[4][16];
    __shared__ float Lsc[4][16];
#pragma unroll
    for (int s = 0; s < 4; ++s)
#pragma unroll
        for (int r = 0; r < 4; ++r)
            Osc[wv][s * 16 + h * 4 + r][c] = acc[s][r];
    if (lane < 16) { Msc[wv][c] = m; Lsc[wv][c] = l; }
    __syncthreads();

#pragma unroll
    for (int ri = 0; ri < 4; ++ri) {
        const int q = wv * 4 + ri;
        float M = fmaxf(fmaxf(Msc[0][q], Msc[1][q]), fmaxf(Msc[2][q], Msc[3][q]));
        float val = 0.f, den = 0.f;
#pragma unroll
        for (int w2 = 0; w2 < 4; ++w2) {
            float sc = exp2f((Msc[w2][q] - M) * L2E);
            den += Lsc[w2][q] * sc;
            val += Osc[w2][lane][q] * sc;
        }
        Og[((size_t)b * NQL + q0 + q) * DVV + lane] = val / den;
    }
}

// ---------------- fallback (round-1 kernel, no workspace needed) ----------------

__global__ __launch_bounds__(256, 4)
void attn_fwd_fb(const float* __restrict__ Qg, const float* __restrict__ Kg,
                 const float* __restrict__ Vg, float* __restrict__ Og)
{
    const int tid  = threadIdx.x;
    const int wv   = tid >> 6;
    const int lane = tid & 63;
    const int c    = lane & 15;
    const int h    = lane >> 4;

    const int bid = blockIdx.x;
    const int b   = bid & 7;
    const int qt  = bid >> 3;
    const int q0  = qt << 4;

    const float* Qb = Qg + (size_t)b * NQL * DD;
    const float* Kb = Kg + (size_t)b * NKL * DD;
    const float* Vb = Vg + (size_t)b * NKL * DVV;

    bf16x8 qf[2];
#pragma unroll
    for (int dh = 0; dh < 2; ++dh) {
        const float* src = Qb + (size_t)(q0 + c) * DD + dh * 32 + h * 8;
        f32x4 x0 = *(const f32x4*)(src);
        f32x4 x1 = *(const f32x4*)(src + 4);
        bf16x8 t;
#pragma unroll
        for (int j = 0; j < 4; ++j) {
            t[j]     = (short)f2bf(x0[j] * 0.125f);
            t[4 + j] = (short)f2bf(x1[j] * 0.125f);
        }
        qf[dh] = t;
    }

    float m = -INFINITY, l = 0.0f;
    f32x4 acc[4];
    {
        f32x4 z = {0.f, 0.f, 0.f, 0.f};
#pragma unroll
        for (int s = 0; s < 4; ++s) acc[s] = z;
    }

    const int nkt = (q0 + 47) >> 5;

    for (int kt = wv; kt < nkt; kt += 4) {
        const int kb = kt << 5;
        f32x4 st[2];
        {
            f32x4 z = {0.f, 0.f, 0.f, 0.f};
            st[0] = z; st[1] = z;
        }
#pragma unroll
        for (int t = 0; t < 2; ++t) {
#pragma unroll
            for (int dh = 0; dh < 2; ++dh) {
                const float* src = Kb + (size_t)(kb + t * 16 + c) * DD + dh * 32 + h * 8;
                f32x4 x0 = *(const f32x4*)(src);
                f32x4 x1 = *(const f32x4*)(src + 4);
                bf16x8 kf;
#pragma unroll
                for (int j = 0; j < 4; ++j) {
                    kf[j]     = (short)f2bf(x0[j]);
                    kf[4 + j] = (short)f2bf(x1[j]);
                }
                st[t] = __builtin_amdgcn_mfma_f32_16x16x32_bf16(kf, qf[dh], st[t], 0, 0, 0);
            }
        }
        if (kb + 31 > q0) {
#pragma unroll
            for (int t = 0; t < 2; ++t)
#pragma unroll
                for (int r = 0; r < 4; ++r) {
                    int key = kb + t * 16 + h * 4 + r;
                    if (key > q0 + c) st[t][r] = -1e9f;
                }
        }
        float vmax = st[0][0];
#pragma unroll
        for (int t = 0; t < 2; ++t)
#pragma unroll
            for (int r = 0; r < 4; ++r) vmax = fmaxf(vmax, st[t][r]);
        vmax = fmaxf(vmax, __shfl_xor(vmax, 16));
        vmax = fmaxf(vmax, __shfl_xor(vmax, 32));
        float mn    = fmaxf(m, vmax);
        float alpha = exp2f((m - mn) * L2E);
        float p[2][4];
        float ps = 0.f;
#pragma unroll
        for (int t = 0; t < 2; ++t)
#pragma unroll
            for (int r = 0; r < 4; ++r) {
                p[t][r] = exp2f((st[t][r] - mn) * L2E);
                ps += p[t][r];
            }
        ps += __shfl_xor(ps, 16);
        ps += __shfl_xor(ps, 32);
        l = l * alpha + ps;
        m = mn;
#pragma unroll
        for (int s = 0; s < 4; ++s)
#pragma unroll
            for (int r = 0; r < 4; ++r) acc[s][r] *= alpha;

        bf16x8 pf;
#pragma unroll
        for (int j = 0; j < 8; ++j) pf[j] = (short)f2bf(p[j >> 2][j & 3]);
        size_t vrow[8];
#pragma unroll
        for (int j = 0; j < 8; ++j)
            vrow[j] = (size_t)(kb + h * 4 + (j & 3) + ((j >> 2) << 4)) * DVV + c;
#pragma unroll
        for (int s = 0; s < 4; ++s) {
            bf16x8 vf;
#pragma unroll
            for (int j = 0; j < 8; ++j) vf[j] = (short)f2bf(Vb[vrow[j] + s * 16]);
            acc[s] = __builtin_amdgcn_mfma_f32_16x16x32_bf16(vf, pf, acc[s], 0, 0, 0);
        }
    }

    __shared__ float Osc[4][64][17];
    __shared__ float Msc[4][16];
    __shared__ float Lsc[4][16];
#pragma unroll
    for (int s = 0; s < 4; ++s)
#pragma unroll
        for (int r = 0; r < 4; ++r)
            Osc[wv][s * 16 + h * 4 + r][c] = acc[s][r];
    if (lane < 16) { Msc[wv][c] = m; Lsc[wv][c] = l; }
    __syncthreads();
#pragma unroll
    for (int ri = 0; ri < 4; ++ri) {
        const int q = wv * 4 + ri;
        float M = fmaxf(fmaxf(Msc[0][q], Msc[1][q]), fmaxf(Msc[2][q], Msc[3][q]));
        float val = 0.f, den = 0.f;
#pragma unroll
        for (int w2 = 0; w2 < 4; ++w2) {
            float sc = exp2f((Msc[w2][q] - M) * L2E);
            den += Lsc[w2][q] * sc;
            val += Osc[w2][lane][q] * sc;
        }
        Og[((size_t)b * NQL + q0 + q) * DVV + lane] = val / den;
    }
}

extern "C" void kernel_launch(void* const* d_in, const int* in_sizes, int n_in,
                              void* d_out, int out_size, void* d_ws, size_t ws_size,
                              hipStream_t stream)
{
    (void)in_sizes; (void)n_in; (void)out_size;
    const float* Q = (const float*)d_in[0];
    const float* K = (const float*)d_in[1];
    const float* V = (const float*)d_in[2];
    float* O = (float*)d_out;

    const size_t kw_elems = (size_t)NB * NKL * DD;    // bf16 K
    const size_t vt_elems = (size_t)NB * DVV * NKL;   // bf16 V^T
    const size_t need = (kw_elems + vt_elems) * sizeof(unsigned short);

    if (ws_size >= need) {
        unsigned short* Kw = (unsigned short*)d_ws;
        unsigned short* Vt = Kw + kw_elems;
        cvt_k<<<dim3(kw_elems / 8 / 256), dim3(256), 0, stream>>>(K, Kw);
        tr_v <<<dim3(NB * (NKL / 64)),    dim3(256), 0, stream>>>(V, Vt);
        attn_fwd2<<<dim3(NB * (NQL / 16)), dim3(256), 0, stream>>>(Q, Kw, Vt, O);
    } else {
        attn_fwd_fb<<<dim3(NB * (NQL / 16)), dim3(256), 0, stream>>>(Q, K, V, O);
    }
}

// Round 3
// 47.204 us; speedup vs baseline: 1.4605x; 1.4605x over previous
//
#include <hip/hip_runtime.h>

#define NB    8
#define NQL   2048
#define NKL   2048
#define DD    64
#define DVV   64
#define CHK   256            // keys per phase-1 block
#define KSTEP 64             // keys per LDS stage step
#define QT    64             // q rows per phase-1 block
#define NQT   (NQL / QT)     // 32
#define MAXKC (NKL / CHK)    // 8

typedef __attribute__((ext_vector_type(8))) short bf16x8;
typedef __attribute__((ext_vector_type(4))) short bf16x4;
typedef __attribute__((ext_vector_type(2))) short bf16x2;
typedef __attribute__((ext_vector_type(4))) float f32x4;

#define L2E 1.44269504088896340736f

__device__ __forceinline__ unsigned short f2bf(float x) {
    union { float f; unsigned u; } v; v.f = x;
    unsigned r = v.u + 0x7FFFu + ((v.u >> 16) & 1u);
    return (unsigned short)(r >> 16);
}

// LDS swizzles (indices in shorts; rows are 64 shorts = 128 B).
// K tile [key][d]: slot = row&7  -> fragment reads are 2-way (free).
__device__ __forceinline__ int kswz(int row, int col) {
    return row * 64 + (col ^ ((row & 7) << 3));
}
// V^T tile [dv][key]: slot = (dv&7)^((dv>>3)&7) -> reads 2-way, writes ~2-way.
__device__ __forceinline__ int vswz(int dv, int col) {
    return dv * 64 + (col ^ ((((dv & 7) ^ ((dv >> 3) & 7))) << 3));
}

// ================= Phase 1: partial flash attention =================
// grid = NB*NQT*MAXKC; block (b, qt, kc) handles 64 q rows x 256 keys.
// 4 waves q-split; K/V staged once per block per 64-key step (bf16, LDS).
__global__ __launch_bounds__(256, 4)
void attn_part(const float* __restrict__ Qg, const float* __restrict__ Kg,
               const float* __restrict__ Vg, float* __restrict__ Op,
               float* __restrict__ Mp, float* __restrict__ Lp)
{
    const int bid = blockIdx.x;
    const int kc  = bid & 7;
    const int qt  = (bid >> 3) & 31;
    const int b   = bid >> 8;
    const int nkeys = QT * qt + QT;               // causal key count for tile
    if (kc * CHK >= nkeys) return;                // inactive chunk
    const int nsteps = min(4, (nkeys - kc * CHK) >> 6);

    const int tid  = threadIdx.x;
    const int wv   = tid >> 6;
    const int lane = tid & 63;
    const int c    = lane & 15;
    const int h    = lane >> 4;
    const int Q0   = qt * QT;
    const int qg   = Q0 + 16 * wv + c;            // this lane's q row

    const float* Qb = Qg + (size_t)b * NQL * DD;
    const float* Kb = Kg + (size_t)b * NKL * DD;
    const float* Vb = Vg + (size_t)b * NKL * DVV;

    __shared__ short Kl[2][64 * 64];
    __shared__ short Vl[2][64 * 64];

    // staging maps
    const int skr = tid >> 2;             // K row 0..63
    const int sdc = (tid & 3) * 16;       // K col base (floats)
    const int vkr = (tid >> 3) << 1;      // V key pair 0,2,..,62
    const int vdc = (tid & 7) * 8;        // V dv base 0..56

    f32x4 kr[4], vr[4];

    // Q fragments (B-operand), 1/sqrt(64) folded. slot (h,j) = Q[qg][dh*32+8h+j]
    bf16x8 qf[2];
#pragma unroll
    for (int dh = 0; dh < 2; ++dh) {
        const float* src = Qb + (size_t)qg * DD + dh * 32 + h * 8;
        f32x4 x0 = *(const f32x4*)(src);
        f32x4 x1 = *(const f32x4*)(src + 4);
        bf16x8 t;
#pragma unroll
        for (int j = 0; j < 4; ++j) {
            t[j]     = (short)f2bf(x0[j] * 0.125f);
            t[4 + j] = (short)f2bf(x1[j] * 0.125f);
        }
        qf[dh] = t;
    }

    // ---- prologue: stage step 0
    {
        const float* kb0 = Kb + (size_t)(kc * CHK + skr) * DD + sdc;
        kr[0] = *(const f32x4*)(kb0);     kr[1] = *(const f32x4*)(kb0 + 4);
        kr[2] = *(const f32x4*)(kb0 + 8); kr[3] = *(const f32x4*)(kb0 + 12);
        const float* vb0 = Vb + (size_t)(kc * CHK + vkr) * DVV + vdc;
        vr[0] = *(const f32x4*)(vb0);       vr[1] = *(const f32x4*)(vb0 + 4);
        vr[2] = *(const f32x4*)(vb0 + DVV); vr[3] = *(const f32x4*)(vb0 + DVV + 4);
        short* Kd = Kl[0]; short* Vd = Vl[0];
#pragma unroll
        for (int i = 0; i < 4; ++i) {
            bf16x4 t;
#pragma unroll
            for (int j = 0; j < 4; ++j) t[j] = (short)f2bf(kr[i][j]);
            *(bf16x4*)(Kd + kswz(skr, sdc + 4 * i)) = t;
        }
#pragma unroll
        for (int j = 0; j < 8; ++j) {
            bf16x2 t;
            t[0] = (short)f2bf(vr[j >> 2][j & 3]);
            t[1] = (short)f2bf(vr[2 + (j >> 2)][j & 3]);
            *(bf16x2*)(Vd + vswz(vdc + j, vkr)) = t;
        }
    }
    __syncthreads();

    float m = -INFINITY, l = 0.0f;
    f32x4 acc[4];
    {
        f32x4 z = {0.f, 0.f, 0.f, 0.f};
#pragma unroll
        for (int s4 = 0; s4 < 4; ++s4) acc[s4] = z;
    }

    for (int s = 0; s < nsteps; ++s) {
        const int pb = s & 1;

        // T14: issue next step's global loads before compute
        if (s + 1 < nsteps) {
            const float* kb0 = Kb + (size_t)(kc * CHK + (s + 1) * KSTEP + skr) * DD + sdc;
            kr[0] = *(const f32x4*)(kb0);     kr[1] = *(const f32x4*)(kb0 + 4);
            kr[2] = *(const f32x4*)(kb0 + 8); kr[3] = *(const f32x4*)(kb0 + 12);
            const float* vb0 = Vb + (size_t)(kc * CHK + (s + 1) * KSTEP + vkr) * DVV + vdc;
            vr[0] = *(const f32x4*)(vb0);       vr[1] = *(const f32x4*)(vb0 + 4);
            vr[2] = *(const f32x4*)(vb0 + DVV); vr[3] = *(const f32x4*)(vb0 + DVV + 4);
        }

        const int kg0 = kc * CHK + s * KSTEP;
        const bool wactive = (kg0 <= Q0 + 16 * wv + 15);   // wave-uniform
        if (wactive) {
            const short* Kd = Kl[pb];
            const short* Vd = Vl[pb];

            // QK^T: 4 x 16-key subtiles, D=64 as two K=32 MFMAs
            f32x4 st[4];
            {
                f32x4 z = {0.f, 0.f, 0.f, 0.f};
#pragma unroll
                for (int t = 0; t < 4; ++t) st[t] = z;
            }
#pragma unroll
            for (int t = 0; t < 4; ++t)
#pragma unroll
                for (int dh = 0; dh < 2; ++dh) {
                    bf16x8 kf = *(const bf16x8*)(Kd + kswz(16 * t + c, dh * 32 + h * 8));
                    st[t] = __builtin_amdgcn_mfma_f32_16x16x32_bf16(kf, qf[dh], st[t], 0, 0, 0);
                }

            // causal mask (only near-diagonal steps; wave-uniform branch)
            if (kg0 + KSTEP - 1 > Q0 + 16 * wv) {
#pragma unroll
                for (int t = 0; t < 4; ++t)
#pragma unroll
                    for (int r = 0; r < 4; ++r) {
                        int key = kg0 + 16 * t + 4 * h + r;
                        if (key > qg) st[t][r] = -1e9f;
                    }
            }

            // online softmax (defer-max, THR=8)
            float vmax = st[0][0];
#pragma unroll
            for (int t = 0; t < 4; ++t)
#pragma unroll
                for (int r = 0; r < 4; ++r) vmax = fmaxf(vmax, st[t][r]);
            vmax = fmaxf(vmax, __shfl_xor(vmax, 16));
            vmax = fmaxf(vmax, __shfl_xor(vmax, 32));

            if (!__all(vmax - m <= 8.0f)) {
                float mn    = fmaxf(m, vmax);
                float alpha = exp2f((m - mn) * L2E);
                l *= alpha;
#pragma unroll
                for (int s4 = 0; s4 < 4; ++s4)
#pragma unroll
                    for (int r = 0; r < 4; ++r) acc[s4][r] *= alpha;
                m = mn;
            }

            float p[4][4];
            float ps = 0.f;
#pragma unroll
            for (int t = 0; t < 4; ++t)
#pragma unroll
                for (int r = 0; r < 4; ++r) {
                    p[t][r] = exp2f((st[t][r] - m) * L2E);
                    ps += p[t][r];
                }
            ps += __shfl_xor(ps, 16);
            ps += __shfl_xor(ps, 32);
            l += ps;

            // P^T fragments: pf[u] slot (h,j) = key 32u + 16(j>>2) + 4h + (j&3)
            bf16x8 pf[2];
#pragma unroll
            for (int u = 0; u < 2; ++u) {
                bf16x8 t;
#pragma unroll
                for (int j = 0; j < 8; ++j) t[j] = (short)f2bf(p[2 * u + (j >> 2)][j & 3]);
                pf[u] = t;
            }

            // PV: V^T fragments from LDS, same slot->key bijection
#pragma unroll
            for (int s4 = 0; s4 < 4; ++s4) {
#pragma unroll
                for (int u = 0; u < 2; ++u) {
                    bf16x4 lo = *(const bf16x4*)(Vd + vswz(c + 16 * s4, 32 * u + 4 * h));
                    bf16x4 hi = *(const bf16x4*)(Vd + vswz(c + 16 * s4, 32 * u + 16 + 4 * h));
                    bf16x8 vf = {lo[0], lo[1], lo[2], lo[3], hi[0], hi[1], hi[2], hi[3]};
                    acc[s4] = __builtin_amdgcn_mfma_f32_16x16x32_bf16(vf, pf[u], acc[s4], 0, 0, 0);
                }
            }
        }

        // write next step's tiles to the other LDS buffer
        if (s + 1 < nsteps) {
            short* Kd = Kl[(s + 1) & 1];
            short* Vd = Vl[(s + 1) & 1];
#pragma unroll
            for (int i = 0; i < 4; ++i) {
                bf16x4 t;
#pragma unroll
                for (int j = 0; j < 4; ++j) t[j] = (short)f2bf(kr[i][j]);
                *(bf16x4*)(Kd + kswz(skr, sdc + 4 * i)) = t;
            }
#pragma unroll
            for (int j = 0; j < 8; ++j) {
                bf16x2 t;
                t[0] = (short)f2bf(vr[j >> 2][j & 3]);
                t[1] = (short)f2bf(vr[2 + (j >> 2)][j & 3]);
                *(bf16x2*)(Vd + vswz(vdc + j, vkr)) = t;
            }
        }
        __syncthreads();
    }

    // ---- store partials: Op[bid][dv][q], Mp/Lp[bid][q]
    const size_t base = (size_t)bid * (QT * DVV);
#pragma unroll
    for (int s4 = 0; s4 < 4; ++s4)
#pragma unroll
        for (int r = 0; r < 4; ++r) {
            int dv = 16 * s4 + 4 * h + r;
            Op[base + (size_t)dv * 64 + 16 * wv + c] = acc[s4][r];
        }
    if (h == 0) {
        Mp[(size_t)bid * 64 + 16 * wv + c] = m;
        Lp[(size_t)bid * 64 + 16 * wv + c] = l;
    }
}

// ================= Phase 2: combine partials =================
__global__ __launch_bounds__(256)
void attn_comb(const float* __restrict__ Op, const float* __restrict__ Mp,
               const float* __restrict__ Lp, float* __restrict__ Og)
{
    const int blk = blockIdx.x;              // b*NQT + qt
    const int qt  = blk & 31;
    const int b   = blk >> 5;
    const int nkc = (qt >> 2) + 1;           // active chunks for this tile
    const int tid = threadIdx.x;
    const int q   = tid & 63;
    const int dg  = tid >> 6;                // dv group (16 each)
    const size_t pb0 = (size_t)blk * MAXKC;

    float M = -INFINITY;
    for (int kc = 0; kc < nkc; ++kc)
        M = fmaxf(M, Mp[(pb0 + kc) * 64 + q]);

    float den = 0.f;
    float val[16];
#pragma unroll
    for (int i = 0; i < 16; ++i) val[i] = 0.f;

    for (int kc = 0; kc < nkc; ++kc) {
        float mk = Mp[(pb0 + kc) * 64 + q];
        float sc = exp2f((mk - M) * L2E);
        den += Lp[(pb0 + kc) * 64 + q] * sc;
        const float* src = Op + (pb0 + kc) * (QT * DVV) + (size_t)(16 * dg) * 64 + q;
#pragma unroll
        for (int i = 0; i < 16; ++i) val[i] += sc * src[(size_t)i * 64];
    }
    float inv = 1.f / den;

    __shared__ float Ot[64][65];
#pragma unroll
    for (int i = 0; i < 16; ++i) Ot[q][16 * dg + i] = val[i] * inv;
    __syncthreads();

    const int row = tid >> 2;
    const int cb  = (tid & 3) * 16;
    float* dst = Og + ((size_t)b * NQL + qt * QT + row) * DVV + cb;
#pragma unroll
    for (int i = 0; i < 4; ++i) {
        f32x4 t = { Ot[row][cb + 4 * i],     Ot[row][cb + 4 * i + 1],
                    Ot[row][cb + 4 * i + 2], Ot[row][cb + 4 * i + 3] };
        *(f32x4*)(dst + 4 * i) = t;
    }
}

// ================= Fallback (round-1 kernel, no workspace) =================
__global__ __launch_bounds__(256, 4)
void attn_fwd_fb(const float* __restrict__ Qg, const float* __restrict__ Kg,
                 const float* __restrict__ Vg, float* __restrict__ Og)
{
    const int tid  = threadIdx.x;
    const int wv   = tid >> 6;
    const int lane = tid & 63;
    const int c    = lane & 15;
    const int h    = lane >> 4;
    const int bid = blockIdx.x;
    const int b   = bid & 7;
    const int qt  = bid >> 3;
    const int q0  = qt << 4;
    const float* Qb = Qg + (size_t)b * NQL * DD;
    const float* Kb = Kg + (size_t)b * NKL * DD;
    const float* Vb = Vg + (size_t)b * NKL * DVV;
    bf16x8 qf[2];
#pragma unroll
    for (int dh = 0; dh < 2; ++dh) {
        const float* src = Qb + (size_t)(q0 + c) * DD + dh * 32 + h * 8;
        f32x4 x0 = *(const f32x4*)(src);
        f32x4 x1 = *(const f32x4*)(src + 4);
        bf16x8 t;
#pragma unroll
        for (int j = 0; j < 4; ++j) {
            t[j]     = (short)f2bf(x0[j] * 0.125f);
            t[4 + j] = (short)f2bf(x1[j] * 0.125f);
        }
        qf[dh] = t;
    }
    float m = -INFINITY, l = 0.0f;
    f32x4 acc[4];
    {
        f32x4 z = {0.f, 0.f, 0.f, 0.f};
#pragma unroll
        for (int s = 0; s < 4; ++s) acc[s] = z;
    }
    const int nkt = (q0 + 47) >> 5;
    for (int kt = wv; kt < nkt; kt += 4) {
        const int kb = kt << 5;
        f32x4 st[2];
        {
            f32x4 z = {0.f, 0.f, 0.f, 0.f};
            st[0] = z; st[1] = z;
        }
#pragma unroll
        for (int t = 0; t < 2; ++t)
#pragma unroll
            for (int dh = 0; dh < 2; ++dh) {
                const float* src = Kb + (size_t)(kb + t * 16 + c) * DD + dh * 32 + h * 8;
                f32x4 x0 = *(const f32x4*)(src);
                f32x4 x1 = *(const f32x4*)(src + 4);
                bf16x8 kf;
#pragma unroll
                for (int j = 0; j < 4; ++j) {
                    kf[j]     = (short)f2bf(x0[j]);
                    kf[4 + j] = (short)f2bf(x1[j]);
                }
                st[t] = __builtin_amdgcn_mfma_f32_16x16x32_bf16(kf, qf[dh], st[t], 0, 0, 0);
            }
        if (kb + 31 > q0) {
#pragma unroll
            for (int t = 0; t < 2; ++t)
#pragma unroll
                for (int r = 0; r < 4; ++r) {
                    int key = kb + t * 16 + h * 4 + r;
                    if (key > q0 + c) st[t][r] = -1e9f;
                }
        }
        float vmax = st[0][0];
#pragma unroll
        for (int t = 0; t < 2; ++t)
#pragma unroll
            for (int r = 0; r < 4; ++r) vmax = fmaxf(vmax, st[t][r]);
        vmax = fmaxf(vmax, __shfl_xor(vmax, 16));
        vmax = fmaxf(vmax, __shfl_xor(vmax, 32));
        float mn    = fmaxf(m, vmax);
        float alpha = exp2f((m - mn) * L2E);
        float p[2][4];
        float ps = 0.f;
#pragma unroll
        for (int t = 0; t < 2; ++t)
#pragma unroll
            for (int r = 0; r < 4; ++r) {
                p[t][r] = exp2f((st[t][r] - mn) * L2E);
                ps += p[t][r];
            }
        ps += __shfl_xor(ps, 16);
        ps += __shfl_xor(ps, 32);
        l = l * alpha + ps;
        m = mn;
#pragma unroll
        for (int s = 0; s < 4; ++s)
#pragma unroll
            for (int r = 0; r < 4; ++r) acc[s][r] *= alpha;
        bf16x8 pf;
#pragma unroll
        for (int j = 0; j < 8; ++j) pf[j] = (short)f2bf(p[j >> 2][j & 3]);
        size_t vrow[8];
#pragma unroll
        for (int j = 0; j < 8; ++j)
            vrow[j] = (size_t)(kb + h * 4 + (j & 3) + ((j >> 2) << 4)) * DVV + c;
#pragma unroll
        for (int s = 0; s < 4; ++s) {
            bf16x8 vf;
#pragma unroll
            for (int j = 0; j < 8; ++j) vf[j] = (short)f2bf(Vb[vrow[j] + s * 16]);
            acc[s] = __builtin_amdgcn_mfma_f32_16x16x32_bf16(vf, pf, acc[s], 0, 0, 0);
        }
    }
    __shared__ float Osc[4][64][17];
    __shared__ float Msc[4][16];
    __shared__ float Lsc[4][16];
#pragma unroll
    for (int s = 0; s < 4; ++s)
#pragma unroll
        for (int r = 0; r < 4; ++r)
            Osc[wv][s * 16 + h * 4 + r][c] = acc[s][r];
    if (lane < 16) { Msc[wv][c] = m; Lsc[wv][c] = l; }
    __syncthreads();
#pragma unroll
    for (int ri = 0; ri < 4; ++ri) {
        const int q = wv * 4 + ri;
        float M = fmaxf(fmaxf(Msc[0][q], Msc[1][q]), fmaxf(Msc[2][q], Msc[3][q]));
        float val = 0.f, den = 0.f;
#pragma unroll
        for (int w2 = 0; w2 < 4; ++w2) {
            float sc = exp2f((Msc[w2][q] - M) * L2E);
            den += Lsc[w2][q] * sc;
            val += Osc[w2][lane][q] * sc;
        }
        Og[((size_t)b * NQL + q0 + q) * DVV + lane] = val / den;
    }
}

extern "C" void kernel_launch(void* const* d_in, const int* in_sizes, int n_in,
                              void* d_out, int out_size, void* d_ws, size_t ws_size,
                              hipStream_t stream)
{
    (void)in_sizes; (void)n_in; (void)out_size;
    const float* Q = (const float*)d_in[0];
    const float* K = (const float*)d_in[1];
    const float* V = (const float*)d_in[2];
    float* O = (float*)d_out;

    const int    nparts   = NB * NQT * MAXKC;         // 2048
    const size_t op_elems = (size_t)nparts * QT * DVV; // 8.4M floats
    const size_t ml_elems = (size_t)nparts * QT;
    const size_t need = (op_elems + 2 * ml_elems) * sizeof(float);

    if (ws_size >= need) {
        float* Op = (float*)d_ws;
        float* Mp = Op + op_elems;
        float* Lp = Mp + ml_elems;
        attn_part<<<dim3(nparts), dim3(256), 0, stream>>>(Q, K, V, Op, Mp, Lp);
        attn_comb<<<dim3(NB * NQT), dim3(256), 0, stream>>>(Op, Mp, Lp, O);
    } else {
        attn_fwd_fb<<<dim3(NB * (NQL / 16)), dim3(256), 0, stream>>>(Q, K, V, O);
    }
}